// Round 1
// baseline (2225.336 us; speedup 1.0000x reference)
//
#include <hip/hip_runtime.h>

// Problem constants
constexpr int NTOK = 16384;   // 8*2048 tokens
constexpr int KCB  = 8192;    // codebook size
constexpr int DDIM = 128;     // dim
constexpr int OUT_MAIN = NTOK * DDIM;   // 2097152

// ---------------------------------------------------------------------------
// normalize rows of z and codebook  (wave per row, 2 floats/lane)
// ---------------------------------------------------------------------------
__global__ __launch_bounds__(256) void norm_k(const float* __restrict__ z,
                                              const float* __restrict__ cb,
                                              float* __restrict__ zn,
                                              float* __restrict__ en) {
  int lane = threadIdx.x & 63;
  int w    = threadIdx.x >> 6;
  int row  = blockIdx.x * 4 + w;
  const float* src;
  float* dst;
  if (row < NTOK) {
    src = z  + (size_t)row * DDIM;
    dst = zn + (size_t)row * DDIM;
  } else {
    int r = row - NTOK;
    src = cb + (size_t)r * DDIM;
    dst = en + (size_t)r * DDIM;
  }
  float2 v = reinterpret_cast<const float2*>(src)[lane];
  float ss = v.x * v.x + v.y * v.y;
#pragma unroll
  for (int m = 1; m < 64; m <<= 1) ss += __shfl_xor(ss, m);
  float rn = 1.0f / fmaxf(sqrtf(ss), 1e-12f);
  reinterpret_cast<float2*>(dst)[lane] = make_float2(v.x * rn, v.y * rn);
}

// ---------------------------------------------------------------------------
// stage a 64-row x 128-d tile from row-major global into LDS transposed [d][r]
// (stride 64 words; microkernel reads have wave-uniform d -> conflict-free)
// ---------------------------------------------------------------------------
__device__ __forceinline__ void stage_tile(float* __restrict__ dst,
                                           const float* __restrict__ src,
                                           int row0, int tid) {
#pragma unroll
  for (int p = 0; p < 8; ++p) {
    int f  = p * 256 + tid;   // 0..2047 float4s
    int r  = f >> 5;          // row 0..63
    int dq = f & 31;          // float4 within row
    float4 v = *reinterpret_cast<const float4*>(src + ((size_t)(row0 + r) << 7) + (dq << 2));
    float* b = dst + (dq << 8) + r;   // (dq*4)*64 + r
    b[0]   = v.x;
    b[64]  = v.y;
    b[128] = v.z;
    b[192] = v.w;
  }
}

// 4x4 fp32 microkernel over full d=128
__device__ __forceinline__ void mk4x4(const float* __restrict__ As,
                                      const float* __restrict__ Bs,
                                      int i4, int j4, float (&s)[4][4]) {
#pragma unroll
  for (int a = 0; a < 4; ++a)
#pragma unroll
    for (int b = 0; b < 4; ++b) s[a][b] = 0.0f;
#pragma unroll 8
  for (int d = 0; d < DDIM; ++d) {
    float4 av = *reinterpret_cast<const float4*>(As + d * 64 + i4);
    float4 bv = *reinterpret_cast<const float4*>(Bs + d * 64 + j4);
    s[0][0] = fmaf(av.x, bv.x, s[0][0]);
    s[0][1] = fmaf(av.x, bv.y, s[0][1]);
    s[0][2] = fmaf(av.x, bv.z, s[0][2]);
    s[0][3] = fmaf(av.x, bv.w, s[0][3]);
    s[1][0] = fmaf(av.y, bv.x, s[1][0]);
    s[1][1] = fmaf(av.y, bv.y, s[1][1]);
    s[1][2] = fmaf(av.y, bv.z, s[1][2]);
    s[1][3] = fmaf(av.y, bv.w, s[1][3]);
    s[2][0] = fmaf(av.z, bv.x, s[2][0]);
    s[2][1] = fmaf(av.z, bv.y, s[2][1]);
    s[2][2] = fmaf(av.z, bv.z, s[2][2]);
    s[2][3] = fmaf(av.z, bv.w, s[2][3]);
    s[3][0] = fmaf(av.w, bv.x, s[3][0]);
    s[3][1] = fmaf(av.w, bv.y, s[3][1]);
    s[3][2] = fmaf(av.w, bv.z, s[3][2]);
    s[3][3] = fmaf(av.w, bv.w, s[3][3]);
  }
}

// ---------------------------------------------------------------------------
// pass 1: block = 64 rows x all K. online argmax + logsumexp (logits = cos*10)
// thread map: i = tid>>4 (row group, rows 4i..4i+3), j = tid&15 (cols 4j..4j+3)
// row-reduce across the 16 consecutive lanes sharing i.
// ---------------------------------------------------------------------------
__global__ __launch_bounds__(256) void pass1(const float* __restrict__ zn,
                                             const float* __restrict__ en,
                                             float* __restrict__ lse,
                                             int* __restrict__ idxb,
                                             int* __restrict__ counts) {
  __shared__ float As[DDIM * 64];
  __shared__ float Bs[DDIM * 64];
  int tid = threadIdx.x;
  int n0  = blockIdx.x * 64;
  int i4  = (tid >> 4) * 4;
  int j   = tid & 15;
  int j4  = j * 4;

  stage_tile(As, zn, n0, tid);

  float M[4], L[4];
  int   A[4];
#pragma unroll
  for (int r = 0; r < 4; ++r) { M[r] = -1e30f; L[r] = 0.0f; A[r] = 0; }

  for (int kt = 0; kt < KCB / 64; ++kt) {
    __syncthreads();
    stage_tile(Bs, en, kt * 64, tid);
    __syncthreads();

    float s[4][4];
    mk4x4(As, Bs, i4, j4, s);

#pragma unroll
    for (int rr = 0; rr < 4; ++rr) {
      // tile argmax (np semantics: first max wins)
      float bv = s[rr][0];
      int   bi = kt * 64 + j4;
#pragma unroll
      for (int cc = 1; cc < 4; ++cc) {
        float v = s[rr][cc];
        int   k = kt * 64 + j4 + cc;
        if (v > bv) { bv = v; bi = k; }
      }
#pragma unroll
      for (int m = 1; m < 16; m <<= 1) {
        float ov = __shfl_xor(bv, m);
        int   oi = __shfl_xor(bi, m);
        if (ov > bv || (ov == bv && oi < bi)) { bv = ov; bi = oi; }
      }
      // online max merge (tiles ascending in k, so strict > keeps first-max)
      if (bv > M[rr]) {
        L[rr] *= __expf((M[rr] - bv) * 10.0f);
        M[rr] = bv;
        A[rr] = bi;
      }
      // tile sum of exp
      float ls = __expf((s[rr][0] - M[rr]) * 10.0f)
               + __expf((s[rr][1] - M[rr]) * 10.0f)
               + __expf((s[rr][2] - M[rr]) * 10.0f)
               + __expf((s[rr][3] - M[rr]) * 10.0f);
#pragma unroll
      for (int m = 1; m < 16; m <<= 1) ls += __shfl_xor(ls, m);
      L[rr] += ls;
    }
  }

  if (j == 0) {
#pragma unroll
    for (int rr = 0; rr < 4; ++rr) {
      int n = n0 + i4 + rr;
      lse[n]  = M[rr] * 10.0f + logf(L[rr]);
      idxb[n] = A[rr];
      atomicAdd(&counts[A[rr]], 1);
    }
  }
}

// ---------------------------------------------------------------------------
// pass 2: recompute scores, accumulate column sums of softmax probs.
// thread map SWAPPED: i = tid&15 (rows), j = tid>>4 (cols) so the 16 threads
// sharing a col-group are consecutive lanes -> shuffle reduce, no LDS/atomics.
// Each block writes its own partial row in Ppart (deterministic).
// ---------------------------------------------------------------------------
__global__ __launch_bounds__(256) void pass2(const float* __restrict__ zn,
                                             const float* __restrict__ en,
                                             const float* __restrict__ lse,
                                             float* __restrict__ Ppart) {
  __shared__ float As[DDIM * 64];
  __shared__ float Bs[DDIM * 64];
  int tid = threadIdx.x;
  int n0  = blockIdx.x * 64;
  int i   = tid & 15;
  int i4  = i * 4;
  int j4  = (tid >> 4) * 4;

  stage_tile(As, zn, n0, tid);

  float nlse[4];
#pragma unroll
  for (int rr = 0; rr < 4; ++rr) nlse[rr] = lse[n0 + i4 + rr];

  float* myP = Ppart + (size_t)blockIdx.x * KCB;

  for (int kt = 0; kt < KCB / 64; ++kt) {
    __syncthreads();
    stage_tile(Bs, en, kt * 64, tid);
    __syncthreads();

    float s[4][4];
    mk4x4(As, Bs, i4, j4, s);

    float pc[4];
#pragma unroll
    for (int cc = 0; cc < 4; ++cc) {
      pc[cc] = __expf(s[0][cc] * 10.0f - nlse[0])
             + __expf(s[1][cc] * 10.0f - nlse[1])
             + __expf(s[2][cc] * 10.0f - nlse[2])
             + __expf(s[3][cc] * 10.0f - nlse[3]);
#pragma unroll
      for (int m = 1; m < 16; m <<= 1) pc[cc] += __shfl_xor(pc[cc], m);
    }
    if (i == 0) {
#pragma unroll
      for (int cc = 0; cc < 4; ++cc) myP[kt * 64 + j4 + cc] = pc[cc];
    }
  }
}

// ---------------------------------------------------------------------------
// gather z_q, emit z_q_ste = z + (z_q - z), block-partial commit sums
// ---------------------------------------------------------------------------
__global__ __launch_bounds__(256) void k3(const float* __restrict__ z,
                                          const float* __restrict__ cb,
                                          const int* __restrict__ idxb,
                                          float* __restrict__ out,
                                          float* __restrict__ cpart) {
  int tid = threadIdx.x;
  int e   = blockIdx.x * 256 + tid;   // float4 index, total N*D/4 = 524288
  int n   = e >> 5;
  int q   = e & 31;
  int id  = idxb[n];
  float4 c4 = reinterpret_cast<const float4*>(cb)[id * 32 + q];
  float4 z4 = reinterpret_cast<const float4*>(z)[e];
  float4 o;
  o.x = z4.x + (c4.x - z4.x);
  o.y = z4.y + (c4.y - z4.y);
  o.z = z4.z + (c4.z - z4.z);
  o.w = z4.w + (c4.w - z4.w);
  reinterpret_cast<float4*>(out)[e] = o;
  float dx = c4.x - z4.x, dy = c4.y - z4.y, dz = c4.z - z4.z, dw = c4.w - z4.w;
  float ds = dx * dx + dy * dy + dz * dz + dw * dw;
#pragma unroll
  for (int m = 1; m < 64; m <<= 1) ds += __shfl_xor(ds, m);
  __shared__ float wsum[4];
  if ((tid & 63) == 0) wsum[tid >> 6] = ds;
  __syncthreads();
  if (tid == 0) cpart[blockIdx.x] = wsum[0] + wsum[1] + wsum[2] + wsum[3];
}

// ---------------------------------------------------------------------------
// reduce Ppart[256][K] -> Psum[K]
// ---------------------------------------------------------------------------
__global__ __launch_bounds__(256) void reduceP(const float* __restrict__ Ppart,
                                               float* __restrict__ Psum) {
  int k = blockIdx.x * 256 + threadIdx.x;   // grid 32 -> 8192 threads
  float s = 0.0f;
  for (int b = 0; b < NTOK / 64; ++b) s += Ppart[(size_t)b * KCB + k];
  Psum[k] = s;
}

// ---------------------------------------------------------------------------
// final scalars: commit, perplexity, entropy_loss, min(ema)
// ---------------------------------------------------------------------------
__global__ __launch_bounds__(256) void finalk(const int* __restrict__ counts,
                                              const float* __restrict__ Psum,
                                              const float* __restrict__ pema,
                                              const float* __restrict__ cpart,
                                              float* __restrict__ out) {
  int tid = threadIdx.x;
  float s1 = 0.0f, s2 = 0.0f, cs = 0.0f, mn = 1e30f;
  const float invN = 1.0f / (float)NTOK;
  const float thr  = 0.0125f / (float)KCB;
  const float invK = 1.0f / (float)KCB;
  for (int k = tid; k < KCB; k += 256) {
    float e = (float)counts[k] * invN;
    s1 += e * logf(e + 1e-8f);
    float pa = Psum[k] * invN + 1e-8f;
    s2 += pa * logf(pa);
    float ema  = 0.9f * pema[k] + 0.1f * e;
    float emaf = (ema < thr) ? invK : ema;   // rank < N always true (K < N)
    mn = fminf(mn, emaf);
  }
  for (int b = tid; b < 2048; b += 256) cs += cpart[b];
#pragma unroll
  for (int m = 1; m < 64; m <<= 1) {
    s1 += __shfl_xor(s1, m);
    s2 += __shfl_xor(s2, m);
    cs += __shfl_xor(cs, m);
    mn = fminf(mn, __shfl_xor(mn, m));
  }
  __shared__ float r1[4], r2[4], r3[4], r4[4];
  if ((tid & 63) == 0) {
    int w = tid >> 6;
    r1[w] = s1; r2[w] = s2; r3[w] = cs; r4[w] = mn;
  }
  __syncthreads();
  if (tid == 0) {
    float S1 = r1[0] + r1[1] + r1[2] + r1[3];
    float S2 = r2[0] + r2[1] + r2[2] + r2[3];
    float CS = r3[0] + r3[1] + r3[2] + r3[3];
    float MN = fminf(fminf(r4[0], r4[1]), fminf(r4[2], r4[3]));
    out[OUT_MAIN + 0] = 1.25f * CS / (float)OUT_MAIN;  // commit_loss
    out[OUT_MAIN + 1] = expf(-S1);                     // perplexity
    out[OUT_MAIN + 2] = -S2;                           // entropy_loss
    out[OUT_MAIN + 3] = MN;                            // min(ema)
  }
}

// ---------------------------------------------------------------------------
extern "C" void kernel_launch(void* const* d_in, const int* in_sizes, int n_in,
                              void* d_out, int out_size, void* d_ws, size_t ws_size,
                              hipStream_t stream) {
  const float* z    = (const float*)d_in[0];
  const float* cb   = (const float*)d_in[1];
  const float* pema = (const float*)d_in[2];
  float* out = (float*)d_out;
  char*  ws  = (char*)d_ws;

  // workspace layout (needs ~21 MB)
  float* zn     = (float*)(ws + 0);                       // 8 MB
  float* en     = (float*)(ws + (8u << 20));              // 4 MB
  float* lse    = (float*)(ws + (12u << 20));             // 64 KB
  int*   idxb   = (int*)  (ws + (12u << 20) + (1u << 16));// 64 KB
  int*   counts = (int*)  (ws + (12u << 20) + (2u << 16));// 32 KB
  float* Psum   = (float*)(ws + (12u << 20) + (2u << 16) + (1u << 15)); // 32 KB
  float* cpart  = (float*)(ws + (12u << 20) + (2u << 16) + (2u << 15)); // 8 KB
  float* Ppart  = (float*)(ws + (13u << 20));             // 8 MB (256 x 8192)

  hipMemsetAsync(counts, 0, KCB * sizeof(int), stream);

  norm_k <<<(NTOK + KCB) / 4, 256, 0, stream>>>(z, cb, zn, en);
  pass1  <<<NTOK / 64,        256, 0, stream>>>(zn, en, lse, idxb, counts);
  pass2  <<<NTOK / 64,        256, 0, stream>>>(zn, en, lse, Ppart);
  k3     <<<NTOK * DDIM / 4 / 256, 256, 0, stream>>>(z, cb, idxb, out, cpart);
  reduceP<<<KCB / 256,        256, 0, stream>>>(Ppart, Psum);
  finalk <<<1,                256, 0, stream>>>(counts, Psum, pema, cpart, out);
}

// Round 3
// 1147.187 us; speedup vs baseline: 1.9398x; 1.9398x over previous
//
#include <hip/hip_runtime.h>
#include <hip/hip_fp16.h>

// Problem constants
constexpr int NTOK = 16384;   // 8*2048 tokens
constexpr int KCB  = 8192;    // codebook size
constexpr int DDIM = 128;     // dim
constexpr int OUT_MAIN = NTOK * DDIM;   // 2097152
constexpr int KHALF = KCB / 2;          // 4096 per k-split half

// ---------------------------------------------------------------------------
// normalize rows of z and codebook  (wave per row, 2 floats/lane)
// ---------------------------------------------------------------------------
__global__ __launch_bounds__(256) void norm_k(const float* __restrict__ z,
                                              const float* __restrict__ cb,
                                              float* __restrict__ zn,
                                              float* __restrict__ en) {
  int lane = threadIdx.x & 63;
  int w    = threadIdx.x >> 6;
  int row  = blockIdx.x * 4 + w;
  const float* src;
  float* dst;
  if (row < NTOK) {
    src = z  + (size_t)row * DDIM;
    dst = zn + (size_t)row * DDIM;
  } else {
    int r = row - NTOK;
    src = cb + (size_t)r * DDIM;
    dst = en + (size_t)r * DDIM;
  }
  float2 v = reinterpret_cast<const float2*>(src)[lane];
  float ss = v.x * v.x + v.y * v.y;
#pragma unroll
  for (int m = 1; m < 64; m <<= 1) ss += __shfl_xor(ss, m);
  float rn = 1.0f / fmaxf(sqrtf(ss), 1e-12f);
  reinterpret_cast<float2*>(dst)[lane] = make_float2(v.x * rn, v.y * rn);
}

// ---------------------------------------------------------------------------
// stage a 64-row x 128-d tile into LDS, layout [d][r] with XOR swizzle:
// physical float index = d*64 + (r ^ ((d>>2 & 7) << 2)).
// Staging mapping gives each wave 4 distinct r values (r0 multiple of 4) and
// 8 distinct swizzle values -> writes hit 32 banks 2-way (free).
// Microkernel reads at wave-uniform d -> swizzle is a uniform permute (free).
// ---------------------------------------------------------------------------
__device__ __forceinline__ void stage_tile(float* __restrict__ dst,
                                           const float* __restrict__ src,
                                           int row0, int tid) {
#pragma unroll
  for (int p = 0; p < 8; ++p) {
    int idx = p * 256 + tid;                        // 0..2047
    int dq  = (idx & 15) | ((idx >> 10) << 4);      // 0..31  (float4 along d)
    int r   = (idx >> 4) & 63;                      // 0..63  (row)
    float4 v = *reinterpret_cast<const float4*>(src + ((size_t)(row0 + r) << 7) + (dq << 2));
    int rp = r ^ ((dq & 7) << 2);
    float* b = dst + (dq << 8) + rp;                // (dq*4)*64 + swizzled r
    b[0]   = v.x;
    b[64]  = v.y;
    b[128] = v.z;
    b[192] = v.w;
  }
}

// 4x4 fp32 microkernel over full d=128 with swizzled reads
__device__ __forceinline__ void mk4x4(const float* __restrict__ As,
                                      const float* __restrict__ Bs,
                                      int i4, int j4, float (&s)[4][4]) {
#pragma unroll
  for (int a = 0; a < 4; ++a)
#pragma unroll
    for (int b = 0; b < 4; ++b) s[a][b] = 0.0f;
  for (int d0 = 0; d0 < DDIM; d0 += 32) {
    const float* Ab = As + d0 * 64;
    const float* Bb = Bs + d0 * 64;
#pragma unroll
    for (int dd = 0; dd < 32; ++dd) {
      const int sw = ((dd >> 2) & 7) << 2;          // compile-time constant
      float4 av = *reinterpret_cast<const float4*>(Ab + dd * 64 + (i4 ^ sw));
      float4 bv = *reinterpret_cast<const float4*>(Bb + dd * 64 + (j4 ^ sw));
      s[0][0] = fmaf(av.x, bv.x, s[0][0]);
      s[0][1] = fmaf(av.x, bv.y, s[0][1]);
      s[0][2] = fmaf(av.x, bv.z, s[0][2]);
      s[0][3] = fmaf(av.x, bv.w, s[0][3]);
      s[1][0] = fmaf(av.y, bv.x, s[1][0]);
      s[1][1] = fmaf(av.y, bv.y, s[1][1]);
      s[1][2] = fmaf(av.y, bv.z, s[1][2]);
      s[1][3] = fmaf(av.y, bv.w, s[1][3]);
      s[2][0] = fmaf(av.z, bv.x, s[2][0]);
      s[2][1] = fmaf(av.z, bv.y, s[2][1]);
      s[2][2] = fmaf(av.z, bv.z, s[2][2]);
      s[2][3] = fmaf(av.z, bv.w, s[2][3]);
      s[3][0] = fmaf(av.w, bv.x, s[3][0]);
      s[3][1] = fmaf(av.w, bv.y, s[3][1]);
      s[3][2] = fmaf(av.w, bv.z, s[3][2]);
      s[3][3] = fmaf(av.w, bv.w, s[3][3]);
    }
  }
}

// ---------------------------------------------------------------------------
// pass 1: grid (N/64, 2). Block = 64 rows x one K-half. Online argmax +
// logsumexp partials per half; optionally cache scores as fp16.
// ---------------------------------------------------------------------------
template <bool CACHED>
__global__ __launch_bounds__(256) void pass1(const float* __restrict__ zn,
                                             const float* __restrict__ en,
                                             __half* __restrict__ scores,
                                             float* __restrict__ Mpart,
                                             int* __restrict__ Apart,
                                             float* __restrict__ Lpart) {
  __shared__ float As[DDIM * 64];
  __shared__ float Bs[DDIM * 64];
  int tid   = threadIdx.x;
  int n0    = blockIdx.x * 64;
  int kh    = blockIdx.y;
  int kbase = kh * KHALF;
  int i4    = (tid >> 4) * 4;
  int j     = tid & 15;
  int j4    = j * 4;

  stage_tile(As, zn, n0, tid);

  float M[4], L[4];
  int   A[4];
#pragma unroll
  for (int r = 0; r < 4; ++r) { M[r] = -1e30f; L[r] = 0.0f; A[r] = 0; }

  for (int kt = 0; kt < KHALF / 64; ++kt) {
    int kcol = kbase + kt * 64;
    __syncthreads();
    stage_tile(Bs, en, kcol, tid);
    __syncthreads();

    float s[4][4];
    mk4x4(As, Bs, i4, j4, s);

    if constexpr (CACHED) {
#pragma unroll
      for (int rr = 0; rr < 4; ++rr) {
        __half2* sp = reinterpret_cast<__half2*>(
            scores + (size_t)(n0 + i4 + rr) * KCB + kcol + j4);
        sp[0] = __floats2half2_rn(s[rr][0], s[rr][1]);
        sp[1] = __floats2half2_rn(s[rr][2], s[rr][3]);
      }
    }

#pragma unroll
    for (int rr = 0; rr < 4; ++rr) {
      // tile argmax (np semantics: first max wins)
      float bv = s[rr][0];
      int   bi = kcol + j4;
#pragma unroll
      for (int cc = 1; cc < 4; ++cc) {
        float v = s[rr][cc];
        int   k = kcol + j4 + cc;
        if (v > bv) { bv = v; bi = k; }
      }
#pragma unroll
      for (int m = 1; m < 16; m <<= 1) {
        float ov = __shfl_xor(bv, m);
        int   oi = __shfl_xor(bi, m);
        if (ov > bv || (ov == bv && oi < bi)) { bv = ov; bi = oi; }
      }
      // online max merge (tiles ascending in k, strict > keeps first-max)
      if (bv > M[rr]) {
        L[rr] *= __expf((M[rr] - bv) * 10.0f);
        M[rr] = bv;
        A[rr] = bi;
      }
      float ls = __expf((s[rr][0] - M[rr]) * 10.0f)
               + __expf((s[rr][1] - M[rr]) * 10.0f)
               + __expf((s[rr][2] - M[rr]) * 10.0f)
               + __expf((s[rr][3] - M[rr]) * 10.0f);
#pragma unroll
      for (int m = 1; m < 16; m <<= 1) ls += __shfl_xor(ls, m);
      L[rr] += ls;
    }
  }

  if (j == 0) {
#pragma unroll
    for (int rr = 0; rr < 4; ++rr) {
      int n = n0 + i4 + rr;
      Mpart[kh * NTOK + n] = M[rr];
      Apart[kh * NTOK + n] = A[rr];
      Lpart[kh * NTOK + n] = L[rr];
    }
  }
}

// ---------------------------------------------------------------------------
// merge the two K-half partials -> lse, idx, counts
// ---------------------------------------------------------------------------
__global__ __launch_bounds__(256) void merge_k(const float* __restrict__ Mpart,
                                               const int* __restrict__ Apart,
                                               const float* __restrict__ Lpart,
                                               float* __restrict__ lse,
                                               int* __restrict__ idxb,
                                               int* __restrict__ counts) {
  int n = blockIdx.x * 256 + threadIdx.x;
  float m0 = Mpart[n], m1 = Mpart[NTOK + n];
  float l0 = Lpart[n], l1 = Lpart[NTOK + n];
  int   a0 = Apart[n], a1 = Apart[NTOK + n];
  float m = fmaxf(m0, m1);
  float l = l0 * __expf((m0 - m) * 10.0f) + l1 * __expf((m1 - m) * 10.0f);
  int   a = (m1 > m0) ? a1 : a0;   // strict > : ties go to lower-index half
  lse[n]  = m * 10.0f + logf(l);
  idxb[n] = a;
  atomicAdd(&counts[a], 1);
}

// ---------------------------------------------------------------------------
// pass 2 (cached): read fp16 scores, accumulate column sums of softmax probs.
// grid (K/512, N/256); thread owns 2 adjacent columns, loops 256 rows.
// ---------------------------------------------------------------------------
__global__ __launch_bounds__(256) void pass2c(const __half* __restrict__ scores,
                                              const float* __restrict__ lse,
                                              float* __restrict__ Ppart) {
  int k0 = blockIdx.x * 512 + threadIdx.x * 2;
  int n0 = blockIdx.y * 256;
  float s0 = 0.0f, s1 = 0.0f;
#pragma unroll 4
  for (int r = 0; r < 256; ++r) {
    int n = n0 + r;
    float nl = lse[n];
    __half2 h = *reinterpret_cast<const __half2*>(scores + (size_t)n * KCB + k0);
    float2 f = __half22float2(h);
    s0 += __expf(f.x * 10.0f - nl);
    s1 += __expf(f.y * 10.0f - nl);
  }
  *reinterpret_cast<float2*>(Ppart + (size_t)blockIdx.y * KCB + k0) =
      make_float2(s0, s1);
}

// ---------------------------------------------------------------------------
// pass 2 (fallback): recompute scores via GEMM. grid (N/64, 2).
// thread map swapped: i = tid&15 (rows), j = tid>>4 (cols)
// ---------------------------------------------------------------------------
__global__ __launch_bounds__(256) void pass2f(const float* __restrict__ zn,
                                              const float* __restrict__ en,
                                              const float* __restrict__ lse,
                                              float* __restrict__ Ppart) {
  __shared__ float As[DDIM * 64];
  __shared__ float Bs[DDIM * 64];
  int tid   = threadIdx.x;
  int n0    = blockIdx.x * 64;
  int kh    = blockIdx.y;
  int kbase = kh * KHALF;
  int i     = tid & 15;
  int i4    = i * 4;
  int j4    = (tid >> 4) * 4;

  stage_tile(As, zn, n0, tid);

  float nlse[4];
#pragma unroll
  for (int rr = 0; rr < 4; ++rr) nlse[rr] = lse[n0 + i4 + rr];

  float* myP = Ppart + (size_t)blockIdx.x * KCB + kbase;

  for (int kt = 0; kt < KHALF / 64; ++kt) {
    __syncthreads();
    stage_tile(Bs, en, kbase + kt * 64, tid);
    __syncthreads();

    float s[4][4];
    mk4x4(As, Bs, i4, j4, s);

    float pc[4];
#pragma unroll
    for (int cc = 0; cc < 4; ++cc) {
      pc[cc] = __expf(s[0][cc] * 10.0f - nlse[0])
             + __expf(s[1][cc] * 10.0f - nlse[1])
             + __expf(s[2][cc] * 10.0f - nlse[2])
             + __expf(s[3][cc] * 10.0f - nlse[3]);
#pragma unroll
      for (int m = 1; m < 16; m <<= 1) pc[cc] += __shfl_xor(pc[cc], m);
    }
    if (i == 0) {
#pragma unroll
      for (int cc = 0; cc < 4; ++cc) myP[kt * 64 + j4 + cc] = pc[cc];
    }
  }
}

// ---------------------------------------------------------------------------
// gather z_q, emit z_q_ste = z + (z_q - z), block-partial commit sums
// ---------------------------------------------------------------------------
__global__ __launch_bounds__(256) void k3(const float* __restrict__ z,
                                          const float* __restrict__ cb,
                                          const int* __restrict__ idxb,
                                          float* __restrict__ out,
                                          float* __restrict__ cpart) {
  int tid = threadIdx.x;
  int e   = blockIdx.x * 256 + tid;   // float4 index, total N*D/4 = 524288
  int n   = e >> 5;
  int q   = e & 31;
  int id  = idxb[n];
  float4 c4 = reinterpret_cast<const float4*>(cb)[id * 32 + q];
  float4 z4 = reinterpret_cast<const float4*>(z)[e];
  float4 o;
  o.x = z4.x + (c4.x - z4.x);
  o.y = z4.y + (c4.y - z4.y);
  o.z = z4.z + (c4.z - z4.z);
  o.w = z4.w + (c4.w - z4.w);
  reinterpret_cast<float4*>(out)[e] = o;
  float dx = c4.x - z4.x, dy = c4.y - z4.y, dz = c4.z - z4.z, dw = c4.w - z4.w;
  float ds = dx * dx + dy * dy + dz * dz + dw * dw;
#pragma unroll
  for (int m = 1; m < 64; m <<= 1) ds += __shfl_xor(ds, m);
  __shared__ float wsum[4];
  if ((tid & 63) == 0) wsum[tid >> 6] = ds;
  __syncthreads();
  if (tid == 0) cpart[blockIdx.x] = wsum[0] + wsum[1] + wsum[2] + wsum[3];
}

// ---------------------------------------------------------------------------
// reduce Ppart[rows][K] -> Psum[K]
// ---------------------------------------------------------------------------
__global__ __launch_bounds__(256) void reduceP(const float* __restrict__ Ppart,
                                               float* __restrict__ Psum,
                                               int rows) {
  int k = blockIdx.x * 256 + threadIdx.x;
  float s = 0.0f;
  for (int b = 0; b < rows; ++b) s += Ppart[(size_t)b * KCB + k];
  Psum[k] = s;
}

// ---------------------------------------------------------------------------
// final scalars: commit, perplexity, entropy_loss, min(ema)
// ---------------------------------------------------------------------------
__global__ __launch_bounds__(256) void finalk(const int* __restrict__ counts,
                                              const float* __restrict__ Psum,
                                              const float* __restrict__ pema,
                                              const float* __restrict__ cpart,
                                              float* __restrict__ out) {
  int tid = threadIdx.x;
  float s1 = 0.0f, s2 = 0.0f, cs = 0.0f, mn = 1e30f;
  const float invN = 1.0f / (float)NTOK;
  const float thr  = 0.0125f / (float)KCB;
  const float invK = 1.0f / (float)KCB;
  for (int k = tid; k < KCB; k += 256) {
    float e = (float)counts[k] * invN;
    s1 += e * logf(e + 1e-8f);
    float pa = Psum[k] * invN + 1e-8f;
    s2 += pa * logf(pa);
    float ema  = 0.9f * pema[k] + 0.1f * e;
    float emaf = (ema < thr) ? invK : ema;   // rank < N always true (K < N)
    mn = fminf(mn, emaf);
  }
  for (int b = tid; b < 2048; b += 256) cs += cpart[b];
#pragma unroll
  for (int m = 1; m < 64; m <<= 1) {
    s1 += __shfl_xor(s1, m);
    s2 += __shfl_xor(s2, m);
    cs += __shfl_xor(cs, m);
    mn = fminf(mn, __shfl_xor(mn, m));
  }
  __shared__ float r1[4], r2[4], r3[4], r4[4];
  if ((tid & 63) == 0) {
    int w = tid >> 6;
    r1[w] = s1; r2[w] = s2; r3[w] = cs; r4[w] = mn;
  }
  __syncthreads();
  if (tid == 0) {
    float S1 = r1[0] + r1[1] + r1[2] + r1[3];
    float S2 = r2[0] + r2[1] + r2[2] + r2[3];
    float CS = r3[0] + r3[1] + r3[2] + r3[3];
    float MN = fminf(fminf(r4[0], r4[1]), fminf(r4[2], r4[3]));
    out[OUT_MAIN + 0] = 1.25f * CS / (float)OUT_MAIN;  // commit_loss
    out[OUT_MAIN + 1] = expf(-S1);                     // perplexity
    out[OUT_MAIN + 2] = -S2;                           // entropy_loss
    out[OUT_MAIN + 3] = MN;                            // min(ema)
  }
}

// ---------------------------------------------------------------------------
extern "C" void kernel_launch(void* const* d_in, const int* in_sizes, int n_in,
                              void* d_out, int out_size, void* d_ws, size_t ws_size,
                              hipStream_t stream) {
  const float* z    = (const float*)d_in[0];
  const float* cb   = (const float*)d_in[1];
  const float* pema = (const float*)d_in[2];
  float* out = (float*)d_out;
  char*  ws  = (char*)d_ws;

  // workspace layout (bytes)
  float* zn     = (float*)(ws + 0);                    // 8 MB
  float* en     = (float*)(ws + (8u << 20));           // 4 MB
  char*  base   = ws + (12u << 20);
  float* lse    = (float*)(base + 0x00000);            // 64 KB
  int*   idxb   = (int*)  (base + 0x10000);            // 64 KB
  int*   counts = (int*)  (base + 0x20000);            // 32 KB
  float* Psum   = (float*)(base + 0x28000);            // 32 KB
  float* cpart  = (float*)(base + 0x30000);            // 8 KB
  float* Mpart  = (float*)(base + 0x40000);            // 128 KB
  int*   Apart  = (int*)  (base + 0x60000);            // 128 KB
  float* Lpart  = (float*)(base + 0x80000);            // 128 KB
  float* Ppart  = (float*)(ws + (13u << 20));          // up to 8 MB
  __half* scores = (__half*)(ws + (21u << 20));        // 256 MB (optional)

  size_t need_cached = (21u << 20) + (size_t)NTOK * KCB * sizeof(__half);
  bool cached = ws_size >= need_cached;

  hipMemsetAsync(counts, 0, KCB * sizeof(int), stream);

  norm_k<<<(NTOK + KCB) / 4, 256, 0, stream>>>(z, cb, zn, en);

  if (cached) {
    pass1<true><<<dim3(NTOK / 64, 2), 256, 0, stream>>>(zn, en, scores, Mpart, Apart, Lpart);
    merge_k<<<NTOK / 256, 256, 0, stream>>>(Mpart, Apart, Lpart, lse, idxb, counts);
    pass2c<<<dim3(KCB / 512, NTOK / 256), 256, 0, stream>>>(scores, lse, Ppart);
    k3<<<NTOK * DDIM / 4 / 256, 256, 0, stream>>>(z, cb, idxb, out, cpart);
    reduceP<<<KCB / 256, 256, 0, stream>>>(Ppart, Psum, NTOK / 256);
  } else {
    pass1<false><<<dim3(NTOK / 64, 2), 256, 0, stream>>>(zn, en, nullptr, Mpart, Apart, Lpart);
    merge_k<<<NTOK / 256, 256, 0, stream>>>(Mpart, Apart, Lpart, lse, idxb, counts);
    pass2f<<<dim3(NTOK / 64, 2), 256, 0, stream>>>(zn, en, lse, Ppart);
    k3<<<NTOK * DDIM / 4 / 256, 256, 0, stream>>>(z, cb, idxb, out, cpart);
    reduceP<<<KCB / 256, 256, 0, stream>>>(Ppart, Psum, NTOK / 64);
  }
  finalk<<<1, 256, 0, stream>>>(counts, Psum, pema, cpart, out);
}

// Round 5
// 581.288 us; speedup vs baseline: 3.8283x; 1.9735x over previous
//
#include <hip/hip_runtime.h>

// Problem constants
constexpr int NTOK = 16384;   // 8*2048 tokens
constexpr int KCB  = 8192;    // codebook size
constexpr int DDIM = 128;     // dim
constexpr int OUT_MAIN = NTOK * DDIM;   // 2097152
constexpr int KSPLIT = 8;
constexpr int KPART  = KCB / KSPLIT;    // 1024 cols per part

typedef __bf16 bf16_t;
typedef bf16_t bf16x8 __attribute__((ext_vector_type(8)));
typedef float  f32x4  __attribute__((ext_vector_type(4)));

__device__ __forceinline__ unsigned short f2bf(float f) {
  unsigned int u = __float_as_uint(f);
  u += 0x7fffu + ((u >> 16) & 1u);      // round-to-nearest-even
  return (unsigned short)(u >> 16);
}

// ---------------------------------------------------------------------------
// normalize rows of z and codebook; emit fp32 (pass1) and bf16 (pass2m) copies
// ---------------------------------------------------------------------------
__global__ __launch_bounds__(256) void norm_k(const float* __restrict__ z,
                                              const float* __restrict__ cb,
                                              float* __restrict__ zn,
                                              float* __restrict__ en,
                                              unsigned short* __restrict__ znb,
                                              unsigned short* __restrict__ enb) {
  int lane = threadIdx.x & 63;
  int w    = threadIdx.x >> 6;
  int row  = blockIdx.x * 4 + w;
  const float* src;
  float* dst;
  unsigned short* dstb;
  if (row < NTOK) {
    src  = z   + (size_t)row * DDIM;
    dst  = zn  + (size_t)row * DDIM;
    dstb = znb + (size_t)row * DDIM;
  } else {
    int r = row - NTOK;
    src  = cb  + (size_t)r * DDIM;
    dst  = en  + (size_t)r * DDIM;
    dstb = enb + (size_t)r * DDIM;
  }
  float2 v = reinterpret_cast<const float2*>(src)[lane];
  float ss = v.x * v.x + v.y * v.y;
#pragma unroll
  for (int m = 1; m < 64; m <<= 1) ss += __shfl_xor(ss, m);
  float rn = 1.0f / fmaxf(sqrtf(ss), 1e-12f);
  float nx = v.x * rn, ny = v.y * rn;
  reinterpret_cast<float2*>(dst)[lane] = make_float2(nx, ny);
  ushort2 b2; b2.x = f2bf(nx); b2.y = f2bf(ny);
  reinterpret_cast<ushort2*>(dstb)[lane] = b2;
}

// ---------------------------------------------------------------------------
// pass 1: fp32 argmax + logsumexp. grid (N/128, KSPLIT). 128x128 tile, BK=32,
// 8x8 per thread. LDS [d][r] with word swizzle r ^ ((d>>2)<<2):
//  - staging writes: 2-way bank aliasing (free)
//  - A-reads: 4 distinct b128 addrs, 16-lane broadcast (free)
//  - B-reads: 16 distinct b128 addrs, 2-way (free)
// ---------------------------------------------------------------------------
__global__ __launch_bounds__(256, 2) void pass1(const float* __restrict__ zn,
                                                const float* __restrict__ en,
                                                float* __restrict__ Mpart,
                                                int* __restrict__ Apart,
                                                float* __restrict__ Lpart) {
  __shared__ float As[32 * 128];
  __shared__ float Bs[32 * 128];
  int tid   = threadIdx.x;
  int n0    = blockIdx.x * 128;
  int part  = blockIdx.y;
  int kbase = part * KPART;
  int i4 = (tid >> 4) * 4;
  int j4 = (tid & 15) * 4;

  float M[8], L[8];
  int   A8[8];
#pragma unroll
  for (int r = 0; r < 8; ++r) { M[r] = -1e30f; L[r] = 0.0f; A8[r] = 0; }

  for (int kt = 0; kt < KPART / 128; ++kt) {
    int k0 = kbase + kt * 128;
    float s[8][8];
#pragma unroll
    for (int a = 0; a < 8; ++a)
#pragma unroll
      for (int b = 0; b < 8; ++b) s[a][b] = 0.0f;

    for (int dc = 0; dc < 4; ++dc) {
      __syncthreads();
      // stage A chunk: 128 rows x 32 d  (transposed [d][r], swizzled)
#pragma unroll
      for (int p = 0; p < 4; ++p) {
        int idx = p * 256 + tid;
        int d4  = idx & 7;          // float4 chunk along d (0..7)
        int r   = idx >> 3;         // row 0..127
        float4 v = *reinterpret_cast<const float4*>(
            zn + (size_t)(n0 + r) * DDIM + dc * 32 + d4 * 4);
        int rp = r ^ (d4 << 2);
        As[(d4 * 4 + 0) * 128 + rp] = v.x;
        As[(d4 * 4 + 1) * 128 + rp] = v.y;
        As[(d4 * 4 + 2) * 128 + rp] = v.z;
        As[(d4 * 4 + 3) * 128 + rp] = v.w;
      }
      // stage B chunk: 128 cols x 32 d
#pragma unroll
      for (int p = 0; p < 4; ++p) {
        int idx = p * 256 + tid;
        int d4  = idx & 7;
        int c   = idx >> 3;
        float4 v = *reinterpret_cast<const float4*>(
            en + (size_t)(k0 + c) * DDIM + dc * 32 + d4 * 4);
        int cp = c ^ (d4 << 2);
        Bs[(d4 * 4 + 0) * 128 + cp] = v.x;
        Bs[(d4 * 4 + 1) * 128 + cp] = v.y;
        Bs[(d4 * 4 + 2) * 128 + cp] = v.z;
        Bs[(d4 * 4 + 3) * 128 + cp] = v.w;
      }
      __syncthreads();
#pragma unroll
      for (int dd = 0; dd < 32; ++dd) {
        const int sw = (dd >> 2) << 2;
        float4 a0 = *reinterpret_cast<const float4*>(As + dd * 128 + (i4 ^ sw));
        float4 a1 = *reinterpret_cast<const float4*>(As + dd * 128 + 64 + (i4 ^ sw));
        float4 b0 = *reinterpret_cast<const float4*>(Bs + dd * 128 + (j4 ^ sw));
        float4 b1 = *reinterpret_cast<const float4*>(Bs + dd * 128 + 64 + (j4 ^ sw));
        float av[8] = {a0.x, a0.y, a0.z, a0.w, a1.x, a1.y, a1.z, a1.w};
        float bv[8] = {b0.x, b0.y, b0.z, b0.w, b1.x, b1.y, b1.z, b1.w};
#pragma unroll
        for (int rr = 0; rr < 8; ++rr)
#pragma unroll
          for (int cc = 0; cc < 8; ++cc)
            s[rr][cc] = fmaf(av[rr], bv[cc], s[rr][cc]);
      }
    }

    // epilogue: online argmax + lse for this 128-col tile
#pragma unroll
    for (int rr = 0; rr < 8; ++rr) {
      float bv = s[rr][0];
      int   bi = k0 + j4;
#pragma unroll
      for (int cc = 1; cc < 8; ++cc) {
        int k = (cc < 4) ? (k0 + j4 + cc) : (k0 + 64 + j4 + cc - 4);
        float v = s[rr][cc];
        if (v > bv) { bv = v; bi = k; }   // ascending k, strict > = first max
      }
#pragma unroll
      for (int m = 1; m < 16; m <<= 1) {
        float ov = __shfl_xor(bv, m);
        int   oi = __shfl_xor(bi, m);
        if (ov > bv || (ov == bv && oi < bi)) { bv = ov; bi = oi; }
      }
      if (bv > M[rr]) {
        L[rr] *= __expf((M[rr] - bv) * 10.0f);
        M[rr] = bv;
        A8[rr] = bi;
      }
      float ls = 0.0f;
#pragma unroll
      for (int cc = 0; cc < 8; ++cc) ls += __expf((s[rr][cc] - M[rr]) * 10.0f);
#pragma unroll
      for (int m = 1; m < 16; m <<= 1) ls += __shfl_xor(ls, m);
      L[rr] += ls;
    }
  }

  if ((tid & 15) == 0) {
#pragma unroll
    for (int rr = 0; rr < 8; ++rr) {
      int n = n0 + ((rr < 4) ? (i4 + rr) : (64 + i4 + rr - 4));
      Mpart[part * NTOK + n] = M[rr];
      Apart[part * NTOK + n] = A8[rr];
      Lpart[part * NTOK + n] = L[rr];
    }
  }
}

// ---------------------------------------------------------------------------
// merge KSPLIT partials -> lse, idx, counts (ascending part order, strict >)
// ---------------------------------------------------------------------------
__global__ __launch_bounds__(256) void merge_k(const float* __restrict__ Mpart,
                                               const int* __restrict__ Apart,
                                               const float* __restrict__ Lpart,
                                               float* __restrict__ lse,
                                               int* __restrict__ idxb,
                                               int* __restrict__ counts) {
  int n = blockIdx.x * 256 + threadIdx.x;
  float M = Mpart[n], L = Lpart[n];
  int   A = Apart[n];
#pragma unroll
  for (int p = 1; p < KSPLIT; ++p) {
    float mp = Mpart[p * NTOK + n], lp = Lpart[p * NTOK + n];
    int   ap = Apart[p * NTOK + n];
    if (mp > M) { L = L * __expf((M - mp) * 10.0f) + lp; M = mp; A = ap; }
    else        { L += lp * __expf((mp - M) * 10.0f); }
  }
  lse[n]  = M * 10.0f + logf(L);
  idxb[n] = A;
  atomicAdd(&counts[A], 1);
}

// ---------------------------------------------------------------------------
// pass 2 (MFMA bf16): recompute scores, accumulate softmax column sums.
// grid (K/64, N/128). Block tile 128 rows x 64 cols, 4 waves (32 rows each).
// LDS tiles row-major bf16 with 16B-chunk swizzle ch ^= (row&7)  (G4 fix).
// MFMA 16x16x32: A row=lane&15 k=(lane>>4)*8+j ; B col=lane&15 (same gather);
// D col=lane&15 row=(lane>>4)*4+reg  [m89-verified family].
// ---------------------------------------------------------------------------
__global__ __launch_bounds__(256) void pass2m(const unsigned short* __restrict__ znb,
                                              const unsigned short* __restrict__ enb,
                                              const float* __restrict__ lse,
                                              float* __restrict__ Ppart) {
  __shared__ unsigned short zt[128 * 128];   // 32 KB
  __shared__ unsigned short et[64 * 128];    // 16 KB
  __shared__ float colbuf[4][64];
  int tid = threadIdx.x;
  int kb = blockIdx.x, nb = blockIdx.y;
  int n0 = nb * 128, k0 = kb * 64;

#pragma unroll
  for (int p = 0; p < 8; ++p) {
    int idx = p * 256 + tid;
    int ch = idx & 15, r = idx >> 4;
    uint4 v = *reinterpret_cast<const uint4*>(znb + (size_t)(n0 + r) * DDIM + ch * 8);
    *reinterpret_cast<uint4*>(&zt[r * 128 + (ch ^ (r & 7)) * 8]) = v;
  }
#pragma unroll
  for (int p = 0; p < 4; ++p) {
    int idx = p * 256 + tid;
    int ch = idx & 15, r = idx >> 4;
    uint4 v = *reinterpret_cast<const uint4*>(enb + (size_t)(k0 + r) * DDIM + ch * 8);
    *reinterpret_cast<uint4*>(&et[r * 128 + (ch ^ (r & 7)) * 8]) = v;
  }
  __syncthreads();

  int wv = tid >> 6, l = tid & 63, lr = l & 15, lk = l >> 4;

  float lse8[2][4];
#pragma unroll
  for (int tr = 0; tr < 2; ++tr)
#pragma unroll
    for (int rg = 0; rg < 4; ++rg)
      lse8[tr][rg] = lse[n0 + wv * 32 + tr * 16 + lk * 4 + rg];

  bf16x8 afr[2][4];
#pragma unroll
  for (int tr = 0; tr < 2; ++tr) {
    int row = wv * 32 + tr * 16 + lr;
#pragma unroll
    for (int dc = 0; dc < 4; ++dc)
      afr[tr][dc] = *reinterpret_cast<const bf16x8*>(
          &zt[row * 128 + ((4 * dc + lk) ^ (row & 7)) * 8]);
  }

#pragma unroll
  for (int ct = 0; ct < 4; ++ct) {
    f32x4 acc0 = {0.f, 0.f, 0.f, 0.f};
    f32x4 acc1 = {0.f, 0.f, 0.f, 0.f};
    int col = ct * 16 + lr;
#pragma unroll
    for (int dc = 0; dc < 4; ++dc) {
      bf16x8 bfr = *reinterpret_cast<const bf16x8*>(
          &et[col * 128 + ((4 * dc + lk) ^ (col & 7)) * 8]);
      acc0 = __builtin_amdgcn_mfma_f32_16x16x32_bf16(afr[0][dc], bfr, acc0, 0, 0, 0);
      acc1 = __builtin_amdgcn_mfma_f32_16x16x32_bf16(afr[1][dc], bfr, acc1, 0, 0, 0);
    }
    float pc = 0.0f;
#pragma unroll
    for (int rg = 0; rg < 4; ++rg) {
      pc += __expf(fmaf(acc0[rg], 10.0f, -lse8[0][rg]));
      pc += __expf(fmaf(acc1[rg], 10.0f, -lse8[1][rg]));
    }
    pc += __shfl_xor(pc, 16);
    pc += __shfl_xor(pc, 32);
    if (l < 16) colbuf[wv][ct * 16 + l] = pc;
  }
  __syncthreads();
  if (tid < 64)
    Ppart[(size_t)nb * KCB + k0 + tid] =
        colbuf[0][tid] + colbuf[1][tid] + colbuf[2][tid] + colbuf[3][tid];
}

// ---------------------------------------------------------------------------
// gather z_q, emit z_q_ste = z + (z_q - z), block-partial commit sums
// ---------------------------------------------------------------------------
__global__ __launch_bounds__(256) void k3(const float* __restrict__ z,
                                          const float* __restrict__ cb,
                                          const int* __restrict__ idxb,
                                          float* __restrict__ out,
                                          float* __restrict__ cpart) {
  int tid = threadIdx.x;
  int e   = blockIdx.x * 256 + tid;   // float4 index, total N*D/4 = 524288
  int n   = e >> 5;
  int q   = e & 31;
  int id  = idxb[n];
  float4 c4 = reinterpret_cast<const float4*>(cb)[id * 32 + q];
  float4 z4 = reinterpret_cast<const float4*>(z)[e];
  float4 o;
  o.x = z4.x + (c4.x - z4.x);
  o.y = z4.y + (c4.y - z4.y);
  o.z = z4.z + (c4.z - z4.z);
  o.w = z4.w + (c4.w - z4.w);
  reinterpret_cast<float4*>(out)[e] = o;
  float dx = c4.x - z4.x, dy = c4.y - z4.y, dz = c4.z - z4.z, dw = c4.w - z4.w;
  float ds = dx * dx + dy * dy + dz * dz + dw * dw;
#pragma unroll
  for (int m = 1; m < 64; m <<= 1) ds += __shfl_xor(ds, m);
  __shared__ float wsum[4];
  if ((tid & 63) == 0) wsum[tid >> 6] = ds;
  __syncthreads();
  if (tid == 0) cpart[blockIdx.x] = wsum[0] + wsum[1] + wsum[2] + wsum[3];
}

// ---------------------------------------------------------------------------
// reduce Ppart[rows][K] -> Psum[K]
// ---------------------------------------------------------------------------
__global__ __launch_bounds__(256) void reduceP(const float* __restrict__ Ppart,
                                               float* __restrict__ Psum,
                                               int rows) {
  int k = blockIdx.x * 256 + threadIdx.x;
  float s = 0.0f;
  for (int b = 0; b < rows; ++b) s += Ppart[(size_t)b * KCB + k];
  Psum[k] = s;
}

// ---------------------------------------------------------------------------
// final scalars: commit, perplexity, entropy_loss, min(ema)
// ---------------------------------------------------------------------------
__global__ __launch_bounds__(256) void finalk(const int* __restrict__ counts,
                                              const float* __restrict__ Psum,
                                              const float* __restrict__ pema,
                                              const float* __restrict__ cpart,
                                              float* __restrict__ out) {
  int tid = threadIdx.x;
  float s1 = 0.0f, s2 = 0.0f, cs = 0.0f, mn = 1e30f;
  const float invN = 1.0f / (float)NTOK;
  const float thr  = 0.0125f / (float)KCB;
  const float invK = 1.0f / (float)KCB;
  for (int k = tid; k < KCB; k += 256) {
    float e = (float)counts[k] * invN;
    s1 += e * logf(e + 1e-8f);
    float pa = Psum[k] * invN + 1e-8f;
    s2 += pa * logf(pa);
    float ema  = 0.9f * pema[k] + 0.1f * e;
    float emaf = (ema < thr) ? invK : ema;   // rank < N always true (K < N)
    mn = fminf(mn, emaf);
  }
  for (int b = tid; b < 2048; b += 256) cs += cpart[b];
#pragma unroll
  for (int m = 1; m < 64; m <<= 1) {
    s1 += __shfl_xor(s1, m);
    s2 += __shfl_xor(s2, m);
    cs += __shfl_xor(cs, m);
    mn = fminf(mn, __shfl_xor(mn, m));
  }
  __shared__ float r1[4], r2[4], r3[4], r4[4];
  if ((tid & 63) == 0) {
    int w = tid >> 6;
    r1[w] = s1; r2[w] = s2; r3[w] = cs; r4[w] = mn;
  }
  __syncthreads();
  if (tid == 0) {
    float S1 = r1[0] + r1[1] + r1[2] + r1[3];
    float S2 = r2[0] + r2[1] + r2[2] + r2[3];
    float CS = r3[0] + r3[1] + r3[2] + r3[3];
    float MN = fminf(fminf(r4[0], r4[1]), fminf(r4[2], r4[3]));
    out[OUT_MAIN + 0] = 1.25f * CS / (float)OUT_MAIN;  // commit_loss
    out[OUT_MAIN + 1] = expf(-S1);                     // perplexity
    out[OUT_MAIN + 2] = -S2;                           // entropy_loss
    out[OUT_MAIN + 3] = MN;                            // min(ema)
  }
}

// ---------------------------------------------------------------------------
extern "C" void kernel_launch(void* const* d_in, const int* in_sizes, int n_in,
                              void* d_out, int out_size, void* d_ws, size_t ws_size,
                              hipStream_t stream) {
  const float* z    = (const float*)d_in[0];
  const float* cb   = (const float*)d_in[1];
  const float* pema = (const float*)d_in[2];
  float* out = (float*)d_out;
  char*  ws  = (char*)d_ws;

  // workspace layout (19.75 MB total; Ppart aliases zn which is dead by then)
  float*          zn   = (float*)(ws + 0);                 // 8 MB
  float*          en   = (float*)(ws + (8u << 20));        // 4 MB
  unsigned short* znb  = (unsigned short*)(ws + (12u << 20)); // 4 MB
  unsigned short* enb  = (unsigned short*)(ws + (16u << 20)); // 2 MB
  char* base = ws + (18u << 20);
  float* lse    = (float*)(base + 0x00000);                // 64 KB
  int*   idxb   = (int*)  (base + 0x10000);                // 64 KB
  int*   counts = (int*)  (base + 0x20000);                // 32 KB
  float* Psum   = (float*)(base + 0x28000);                // 32 KB
  float* cpart  = (float*)(base + 0x30000);                // 8 KB
  float* Mpart  = (float*)(base + 0x40000);                // 512 KB
  int*   Apart  = (int*)  (base + 0xC0000);                // 512 KB
  float* Lpart  = (float*)(base + 0x140000);               // 512 KB
  float* Ppart  = (float*)(ws + 0);                        // 4 MB (aliases zn)

  hipMemsetAsync(counts, 0, KCB * sizeof(int), stream);

  norm_k<<<(NTOK + KCB) / 4, 256, 0, stream>>>(z, cb, zn, en, znb, enb);
  pass1 <<<dim3(NTOK / 128, KSPLIT), 256, 0, stream>>>(zn, en, Mpart, Apart, Lpart);
  merge_k<<<NTOK / 256, 256, 0, stream>>>(Mpart, Apart, Lpart, lse, idxb, counts);
  pass2m<<<dim3(KCB / 64, NTOK / 128), 256, 0, stream>>>(znb, enb, lse, Ppart);
  k3    <<<NTOK * DDIM / 4 / 256, 256, 0, stream>>>(z, cb, idxb, out, cpart);
  reduceP<<<KCB / 256, 256, 0, stream>>>(Ppart, Psum, NTOK / 128);
  finalk<<<1, 256, 0, stream>>>(counts, Psum, pema, cpart, out);
}